// Round 9
// baseline (324.919 us; speedup 1.0000x reference)
//
#include <hip/hip_runtime.h>
#include <hip/hip_bf16.h>

#define NN  50000
#define NE  1600000
#define DIM 64
#define NBK 391          // 128-node buckets

// ---- ws layout (int32 offsets) -------------------------------------------
#define OFF_FLAGS 0          // 8 ints
#define OFF_BOFF  8          // 392: bucket counts -> exclusive offsets
#define OFF_BCUR  400        // 391 bucket cursors (pad to 800)
#define OFF_EIDX  800        // packed records (bucket-grouped)

#define CHUNK 4096   // edges per k_parta block
#define SBCAP 8192   // max records per bucket for LDS sort (expected ~4092)

typedef __bf16 bf16x8 __attribute__((ext_vector_type(8)));
typedef __bf16 bf16x4 __attribute__((ext_vector_type(4)));
typedef float  f32x4  __attribute__((ext_vector_type(4)));

__device__ __forceinline__ float loadF(const void* p, int i, int bf) {
  if (bf) return __bfloat162float(((const __hip_bfloat16*)p)[i]);
  return ((const float*)p)[i];
}

__device__ __forceinline__ float4 loadF4(const void* p, int i4, int bf) {
  if (bf) {
    ushort4 u = ((const ushort4*)p)[i4];
    float4 f;
    union { unsigned int ui; float fl; } c;
    c.ui = (unsigned int)u.x << 16; f.x = c.fl;
    c.ui = (unsigned int)u.y << 16; f.y = c.fl;
    c.ui = (unsigned int)u.z << 16; f.z = c.fl;
    c.ui = (unsigned int)u.w << 16; f.w = c.fl;
    return f;
  }
  return ((const float4*)p)[i4];
}

// Per-array dtype detection + zero bucket counts.
__global__ void k_detect(const void* input, const void* boundary,
                         const void* relw, const void* W, const void* ew,
                         int* flags, int* boff) {
  __shared__ int cnt;
  int t = threadIdx.x;  // 64 threads
  const void* arrs[4] = {input, boundary, relw, W};
  for (int a = 0; a < 4; ++a) {
    if (t == 0) cnt = 0;
    __syncthreads();
    const unsigned short* u = (const unsigned short*)arrs[a];
    unsigned ex = (u[2 * t] >> 7) & 0xFF;
    if (ex >= 100 && ex <= 140) atomicAdd(&cnt, 1);
    __syncthreads();
    if (t == 0) flags[a] = (cnt >= 32) ? 1 : 0;
    __syncthreads();
  }
  if (t == 0) {
    flags[4] = (((const unsigned short*)ew)[0] == 0x3F80) ? 1 : 0;
    flags[5] = 1;
  }
  for (int i = t; i < 392; i += 64) boff[i] = 0;
}

// Bucket-level histogram (LDS-privatized) + exact all-ones check of ew.
__global__ __launch_bounds__(256) void k_bhist(const int* __restrict__ el,
                                               const void* __restrict__ ew,
                                               int* __restrict__ bcnt,
                                               int* __restrict__ flags) {
  __shared__ int lc[NBK];
  int t = threadIdx.x;
  int bfE = flags[4];
  for (int i = t; i < NBK; i += 256) lc[i] = 0;
  __syncthreads();
  int c0 = blockIdx.x * 8192;
  int bad = 0;
  for (int i = t; i < 8192; i += 256) {
    int e = c0 + i;
    if (e < NE) {
      atomicAdd(&lc[el[e * 3 + 1] >> 7], 1);
      if (loadF(ew, e, bfE) != 1.0f) bad = 1;
    }
  }
  if (bad) flags[5] = 0;
  __syncthreads();
  for (int i = t; i < NBK; i += 256)
    if (lc[i]) atomicAdd(&bcnt[i], lc[i]);
}

// Exclusive scan of 392 bucket counts (pair trick); init cursors.
__global__ __launch_bounds__(256) void k_scanb(int* __restrict__ boff,
                                               int* __restrict__ bcur) {
  __shared__ int sc[256];
  int t = threadIdx.x;
  int i0 = 2 * t, i1 = 2 * t + 1;
  int a = (i0 < 392) ? boff[i0] : 0;
  int b = (i1 < 392) ? boff[i1] : 0;
  sc[t] = a + b;
  __syncthreads();
  for (int off = 1; off < 256; off <<= 1) {
    int v = (t >= off) ? sc[t - off] : 0;
    __syncthreads();
    sc[t] += v;
    __syncthreads();
  }
  int excl = sc[t] - (a + b);
  if (i0 < 392) boff[i0] = excl;
  if (i1 < 392) boff[i1] = excl + a;
  if (i0 < NBK) bcur[i0] = excl;
  if (i1 < NBK) bcur[i1] = excl + a;
}

// Partition edges into per-bucket regions via LDS staging (contiguous runs).
// rec = nin|rel<<16|local<<25 (ones) or e|local<<25 (generic).
__global__ __launch_bounds__(256) void k_parta(
    const int* __restrict__ el, int* __restrict__ bcur,
    int* __restrict__ eidx, const int* __restrict__ flags,
    const int* __restrict__ boff, int gb0, int gb1, int cap) {
  __shared__ int stage[CHUNK];
  __shared__ unsigned short sbk[CHUNK];
  __shared__ int lh[NBK], lbase[NBK], lh2[NBK], gbs[NBK];
  __shared__ int sc[256];
  __shared__ int total;
  int t = threadIdx.x;
  int nb = gb1 - gb0;
  int c0 = blockIdx.x * CHUNK;
  int ones = flags[5];
  int base0 = boff[gb0];
  for (int i = t; i < nb; i += 256) { lh[i] = 0; lh2[i] = 0; }
  __syncthreads();
  for (int i = t; i < CHUNK; i += 256) {
    int e = c0 + i;
    if (e < NE) {
      int b = (el[e * 3 + 1] >> 7) - gb0;
      if (b >= 0 && b < nb) atomicAdd(&lh[b], 1);
    }
  }
  __syncthreads();
  int a0 = (2 * t < nb) ? lh[2 * t] : 0;
  int a1 = (2 * t + 1 < nb) ? lh[2 * t + 1] : 0;
  sc[t] = a0 + a1;
  __syncthreads();
  for (int off = 1; off < 256; off <<= 1) {
    int v = (t >= off) ? sc[t - off] : 0;
    __syncthreads();
    sc[t] += v;
    __syncthreads();
  }
  int excl = sc[t] - (a0 + a1);
  if (2 * t < nb) {
    lbase[2 * t] = excl;
    if (a0 > 0) gbs[2 * t] = atomicAdd(&bcur[gb0 + 2 * t], a0);
  }
  if (2 * t + 1 < nb) {
    lbase[2 * t + 1] = excl + a0;
    if (a1 > 0) gbs[2 * t + 1] = atomicAdd(&bcur[gb0 + 2 * t + 1], a1);
  }
  if (t == 255) total = sc[255];
  __syncthreads();
  for (int i = t; i < CHUNK; i += 256) {
    int e = c0 + i;
    if (e < NE) {
      int nout = el[e * 3 + 1];
      int b = (nout >> 7) - gb0;
      if (b >= 0 && b < nb) {
        int r = atomicAdd(&lh2[b], 1);
        int slot = lbase[b] + r;
        int rec = ones ? (el[e * 3] | (el[e * 3 + 2] << 16) |
                          ((nout & 127) << 25))
                       : (e | ((nout & 127) << 25));
        stage[slot] = rec;
        sbk[slot] = (unsigned short)b;
      }
    }
  }
  __syncthreads();
  int tot = total;
  for (int i = t; i < tot; i += 256) {
    int b = sbk[i];
    int dst = gbs[b] + (i - lbase[b]) - base0;
    if (dst >= 0 && dst < cap) eidx[dst] = stage[i];
  }
}

// Fused: per-bucket LDS node-sort + edge gather/variance + MFMA epilogue.
// Block = one 128-node bucket. Waves process 4 nodes each per 16-node group;
// epilogue: OUT(16x64) = bf16(upd)(16x64) @ bf16(W)^T via 2 MFMA per wave.
__global__ __launch_bounds__(256) void k_nodeb(
    const void* __restrict__ input, const void* __restrict__ boundary,
    const int* __restrict__ el, const void* __restrict__ ew,
    const void* __restrict__ relw, const void* __restrict__ W,
    const void* __restrict__ bv, const int* __restrict__ boff,
    const int* __restrict__ eidx, const int* __restrict__ flags,
    void* __restrict__ out, int gb0, int cap) {
  __shared__ int ld[SBCAP];
  __shared__ int lcnt[128], lexc[128];
  __shared__ __bf16 updb[16][72];   // stride 72: breaks 128B-bank aliasing

  int bfI = flags[0], bfB = flags[1], bfR = flags[2], bfW = flags[3],
      bfE = flags[4], ones = flags[5];
  int t  = threadIdx.x;
  int wv = t >> 6, ln = t & 63;
  int g  = ln >> 4;          // edge sub-slot group
  int k  = ln & 15;          // float4 index (edge phase)
  int q  = ln >> 4;          // MFMA quad
  int b  = gb0 + blockIdx.x;
  int n0 = b * 128;
  int base0 = boff[gb0];
  int rbase = boff[b], rend = boff[b + 1];
  int cnt = rend - rbase;
  int off = rbase - base0;
  bool fast = (cnt <= SBCAP) && (rend - base0 <= cap);

  // Per-wave epilogue B-fragments (cols cc = wv*16 + (ln&15)) and bias.
  int cc = wv * 16 + (ln & 15);
  bf16x8 bf0, bf1;
  #pragma unroll
  for (int j = 0; j < 8; ++j) {
    bf0[j] = (__bf16)loadF(W, cc * 64 + q * 8 + j, bfW);
    bf1[j] = (__bf16)loadF(W, cc * 64 + 32 + q * 8 + j, bfW);
  }
  float bias = loadF(bv, cc, bfW);

  // ---- in-LDS counting sort of this bucket's records by local node ----
  if (t < 128) lcnt[t] = 0;
  __syncthreads();
  if (fast)
    for (int i = t; i < cnt; i += 256)
      atomicAdd(&lcnt[(((unsigned)eidx[off + i]) >> 25) & 127], 1);
  __syncthreads();
  if (t < 128) lexc[t] = lcnt[t];
  __syncthreads();
  for (int o = 1; o < 128; o <<= 1) {
    int v = 0;
    if (t < 128 && t >= o) v = lexc[t - o];
    __syncthreads();
    if (t < 128) lexc[t] += v;
    __syncthreads();
  }
  if (t < 128) lexc[t] -= lcnt[t];
  __syncthreads();
  if (t < 128) lcnt[t] = 0;
  __syncthreads();
  if (fast) {
    for (int i = t; i < cnt; i += 256) {
      int rec = eidx[off + i];
      int l = (((unsigned)rec) >> 25) & 127;
      int r = atomicAdd(&lcnt[l], 1);
      ld[lexc[l] + r] = rec;
    }
  }
  __syncthreads();

  const float4* inp4 = (const float4*)input;
  const float4* rw4  = (const float4*)relw;
  int hot = (!bfI && !bfR && ones) ? 1 : 0;

  for (int g16 = 0; g16 < 128; g16 += 16) {
    // ---- edge phase: wave wv computes nodes g16 + wv*4 + {0..3} ----
    for (int rr = 0; rr < 4; ++rr) {
      int l = g16 + wv * 4 + rr;
      int n = n0 + l;
      int row = wv * 4 + rr;
      if (n >= NN) {
        updb[row][ln] = (__bf16)0.0f;   // zero pad row
        continue;
      }
      if (fast) {
        int st = lexc[l], cl = lcnt[l];
        float4 s4 = {0.f,0.f,0.f,0.f}, q4 = {0.f,0.f,0.f,0.f};
        if (hot) {
          for (int base = 0; base < cl; base += 64) {
            int mm = cl - base; if (mm > 64) mm = 64;
            int rec = 0;
            if (ln < mm) rec = ld[st + base + ln];
            int jmax = (mm + 3) >> 2;
            #pragma unroll 8
            for (int j = 0; j < jmax; ++j) {
              int slot = j * 4 + g;
              int pk = __shfl(rec, slot);
              float wsel = (slot < mm) ? 1.0f : 0.0f;
              int nin = pk & 0xFFFF, rl = (pk >> 16) & 0x1FF;
              float4 a = inp4[nin * 16 + k];
              float4 r = rw4[rl * 16 + k];
              float tx = a.x*r.x, ty = a.y*r.y, tz = a.z*r.z, tw = a.w*r.w;
              s4.x = fmaf(wsel, tx, s4.x); q4.x = fmaf(wsel, tx*tx, q4.x);
              s4.y = fmaf(wsel, ty, s4.y); q4.y = fmaf(wsel, ty*ty, q4.y);
              s4.z = fmaf(wsel, tz, s4.z); q4.z = fmaf(wsel, tz*tz, q4.z);
              s4.w = fmaf(wsel, tw, s4.w); q4.w = fmaf(wsel, tw*tw, q4.w);
            }
          }
        } else {
          for (int base = 0; base < cl; base += 64) {
            int mm = cl - base; if (mm > 64) mm = 64;
            int rec = 0; float wrec = 0.0f;
            if (ln < mm) {
              rec = ld[st + base + ln] & 0x1FFFFFF;
              if (!ones) wrec = loadF(ew, rec, bfE);
            }
            int jmax = (mm + 3) >> 2;
            for (int j = 0; j < jmax; ++j) {
              int slot = j * 4 + g;
              int rj = __shfl(rec, slot);
              int nin, rl; float wj;
              if (ones) { nin = rj & 0xFFFF; rl = (rj >> 16) & 0x1FF; wj = 1.0f; }
              else      { nin = el[rj * 3]; rl = el[rj * 3 + 2];
                          wj = __shfl(wrec, slot); }
              float wsel = (slot < mm) ? wj : 0.0f;
              float4 a = loadF4(input, nin * 16 + k, bfI);
              float4 r = loadF4(relw, rl * 16 + k, bfR);
              float tx = a.x*r.x, ty = a.y*r.y, tz = a.z*r.z, tw = a.w*r.w;
              s4.x = fmaf(wsel, tx, s4.x); q4.x = fmaf(wsel*tx, tx, q4.x);
              s4.y = fmaf(wsel, ty, s4.y); q4.y = fmaf(wsel*ty, ty, q4.y);
              s4.z = fmaf(wsel, tz, s4.z); q4.z = fmaf(wsel*tz, tz, q4.z);
              s4.w = fmaf(wsel, tw, s4.w); q4.w = fmaf(wsel*tw, tw, q4.w);
            }
          }
        }
        s4.x += __shfl_xor(s4.x, 16); s4.x += __shfl_xor(s4.x, 32);
        s4.y += __shfl_xor(s4.y, 16); s4.y += __shfl_xor(s4.y, 32);
        s4.z += __shfl_xor(s4.z, 16); s4.z += __shfl_xor(s4.z, 32);
        s4.w += __shfl_xor(s4.w, 16); s4.w += __shfl_xor(s4.w, 32);
        q4.x += __shfl_xor(q4.x, 16); q4.x += __shfl_xor(q4.x, 32);
        q4.y += __shfl_xor(q4.y, 16); q4.y += __shfl_xor(q4.y, 32);
        q4.z += __shfl_xor(q4.z, 16); q4.z += __shfl_xor(q4.z, 32);
        q4.w += __shfl_xor(q4.w, 16); q4.w += __shfl_xor(q4.w, 32);
        if (g == 0) {
          float4 b4 = loadF4(boundary, n * 16 + k, bfB);
          float dg = (float)cl + 1.0f;
          float sv, qv;
          bf16x4 u;
          sv = (s4.x + b4.x) / dg; qv = (q4.x + b4.x * b4.x) / dg;
          u[0] = (__bf16)sqrtf(fmaxf(qv - sv * sv, 1e-6f));
          sv = (s4.y + b4.y) / dg; qv = (q4.y + b4.y * b4.y) / dg;
          u[1] = (__bf16)sqrtf(fmaxf(qv - sv * sv, 1e-6f));
          sv = (s4.z + b4.z) / dg; qv = (q4.z + b4.z * b4.z) / dg;
          u[2] = (__bf16)sqrtf(fmaxf(qv - sv * sv, 1e-6f));
          sv = (s4.w + b4.w) / dg; qv = (q4.w + b4.w * b4.w) / dg;
          u[3] = (__bf16)sqrtf(fmaxf(qv - sv * sv, 1e-6f));
          *(bf16x4*)&updb[row][4 * k] = u;
        }
      } else {
        // correctness-only fallback: ballot-scan el for this node
        float s = 0.f, sq = 0.f; int deg = 0;
        for (int base = 0; base < NE; base += 64) {
          int e = base + ln;
          bool m = (e < NE) && (el[e * 3 + 1] == n);
          unsigned long long msk = __ballot(m);
          deg += (int)__popcll(msk);
          while (msk) {
            int src = __ffsll((long long)msk) - 1; msk &= msk - 1;
            int ee = base + src;
            int nin = el[ee * 3], rl = el[ee * 3 + 2];
            float w = ones ? 1.0f : loadF(ew, ee, bfE);
            float x = loadF(input, nin * 64 + ln, bfI) *
                      loadF(relw, rl * 64 + ln, bfR) * w;
            s += x; sq += x * x;
          }
        }
        float bb = loadF(boundary, n * 64 + ln, bfB);
        s += bb; sq += bb * bb;
        float dg = (float)deg + 1.0f;
        float sv = s / dg, qv = sq / dg;
        updb[row][ln] = (__bf16)sqrtf(fmaxf(qv - sv * sv, 1e-6f));
      }
    }
    __syncthreads();
    // ---- MFMA epilogue for this 16-node group ----
    bf16x8 af0 = *(const bf16x8*)&updb[ln & 15][q * 8];
    bf16x8 af1 = *(const bf16x8*)&updb[ln & 15][32 + q * 8];
    f32x4 acc = {0.f, 0.f, 0.f, 0.f};
    acc = __builtin_amdgcn_mfma_f32_16x16x32_bf16(af0, bf0, acc, 0, 0, 0);
    acc = __builtin_amdgcn_mfma_f32_16x16x32_bf16(af1, bf1, acc, 0, 0, 0);
    #pragma unroll
    for (int i = 0; i < 4; ++i) {
      int row = q * 4 + i;
      int n = n0 + g16 + row;
      if (n < NN) {
        float v = acc[i] + bias;
        if (bfI) ((__hip_bfloat16*)out)[n * 64 + cc] = __float2bfloat16(v);
        else     ((float*)out)[n * 64 + cc] = v;
      }
    }
    __syncthreads();
  }
}

extern "C" void kernel_launch(void* const* d_in, const int* in_sizes, int n_in,
                              void* d_out, int out_size, void* d_ws, size_t ws_size,
                              hipStream_t stream) {
  const void* input    = d_in[0];
  const void* boundary = d_in[1];
  const int*  edges    = (const int*)d_in[2];
  const void* eweight  = d_in[3];
  const void* relw     = d_in[4];
  const void* W        = d_in[5];
  const void* bv       = d_in[6];

  int* wsI   = (int*)d_ws;
  int* flags = wsI + OFF_FLAGS;
  int* boff  = wsI + OFF_BOFF;
  int* bcur  = wsI + OFF_BCUR;
  int* eidx  = wsI + OFF_EIDX;

  long cap = (long)(ws_size / 4) - OFF_EIDX;
  if (cap < 1) cap = 1;
  int npass;
  if      (cap >= (long)NE) npass = 1;
  else if (cap >= 1000000)  npass = 2;
  else if (cap >= 520000)   npass = 4;
  else                      npass = 8;

  k_detect<<<1, 64, 0, stream>>>(input, boundary, relw, W, eweight,
                                 flags, boff);
  k_bhist<<<(NE + 8191) / 8192, 256, 0, stream>>>(edges, eweight, boff, flags);
  k_scanb<<<1, 256, 0, stream>>>(boff, bcur);

  const int PA_NB = (NE + CHUNK - 1) / CHUNK;
  for (int p = 0; p < npass; ++p) {
    int gb0 = NBK * p / npass;
    int gb1 = NBK * (p + 1) / npass;
    k_parta<<<PA_NB, 256, 0, stream>>>(edges, bcur, eidx, flags, boff,
                                       gb0, gb1, (int)cap);
    k_nodeb<<<gb1 - gb0, 256, 0, stream>>>(input, boundary, edges, eweight,
                                           relw, W, bv, boff, eidx, flags,
                                           d_out, gb0, (int)cap);
  }
}

// Round 10
// 244.283 us; speedup vs baseline: 1.3301x; 1.3301x over previous
//
#include <hip/hip_runtime.h>
#include <hip/hip_bf16.h>

#define NN  50000
#define NE  1600000
#define DIM 64
#define NBK 391          // 128-node buckets

// ---- ws layout (int32 offsets) -------------------------------------------
#define OFF_FLAGS  0            // 8 ints
#define OFF_BOFF   8            // 392: bucket counts -> exclusive offsets
#define OFF_BCUR   400          // 391 bucket cursors (pad to 792)
#define OFF_ROWPTR 792          // NN+1 (pad to 50800)
#define OFF_EIDX   50800        // packed records (bucket-grouped)

#define CHUNK 4096   // edges per k_parta block
#define SBCAP 8192   // max records per bucket for LDS sort (expected ~4092)

typedef __bf16 bf16x8 __attribute__((ext_vector_type(8)));
typedef __bf16 bf16x4 __attribute__((ext_vector_type(4)));
typedef float  f32x4  __attribute__((ext_vector_type(4)));

__device__ __forceinline__ float loadF(const void* p, int i, int bf) {
  if (bf) return __bfloat162float(((const __hip_bfloat16*)p)[i]);
  return ((const float*)p)[i];
}

__device__ __forceinline__ float4 loadF4(const void* p, int i4, int bf) {
  if (bf) {
    ushort4 u = ((const ushort4*)p)[i4];
    float4 f;
    union { unsigned int ui; float fl; } c;
    c.ui = (unsigned int)u.x << 16; f.x = c.fl;
    c.ui = (unsigned int)u.y << 16; f.y = c.fl;
    c.ui = (unsigned int)u.z << 16; f.z = c.fl;
    c.ui = (unsigned int)u.w << 16; f.w = c.fl;
    return f;
  }
  return ((const float4*)p)[i4];
}

// Per-array dtype detection + zero bucket counts.
__global__ void k_detect(const void* input, const void* boundary,
                         const void* relw, const void* W, const void* ew,
                         int* flags, int* boff) {
  __shared__ int cnt;
  int t = threadIdx.x;  // 64 threads
  const void* arrs[4] = {input, boundary, relw, W};
  for (int a = 0; a < 4; ++a) {
    if (t == 0) cnt = 0;
    __syncthreads();
    const unsigned short* u = (const unsigned short*)arrs[a];
    unsigned ex = (u[2 * t] >> 7) & 0xFF;
    if (ex >= 100 && ex <= 140) atomicAdd(&cnt, 1);
    __syncthreads();
    if (t == 0) flags[a] = (cnt >= 32) ? 1 : 0;
    __syncthreads();
  }
  if (t == 0) {
    flags[4] = (((const unsigned short*)ew)[0] == 0x3F80) ? 1 : 0;
    flags[5] = 1;
  }
  for (int i = t; i < 392; i += 64) boff[i] = 0;
}

// Bucket-level histogram (LDS-privatized) + exact all-ones check of ew.
__global__ __launch_bounds__(256) void k_bhist(const int* __restrict__ el,
                                               const void* __restrict__ ew,
                                               int* __restrict__ bcnt,
                                               int* __restrict__ flags) {
  __shared__ int lc[NBK];
  int t = threadIdx.x;
  int bfE = flags[4];
  for (int i = t; i < NBK; i += 256) lc[i] = 0;
  __syncthreads();
  int c0 = blockIdx.x * 8192;
  int bad = 0;
  for (int i = t; i < 8192; i += 256) {
    int e = c0 + i;
    if (e < NE) {
      atomicAdd(&lc[el[e * 3 + 1] >> 7], 1);
      if (loadF(ew, e, bfE) != 1.0f) bad = 1;
    }
  }
  if (bad) flags[5] = 0;
  __syncthreads();
  for (int i = t; i < NBK; i += 256)
    if (lc[i]) atomicAdd(&bcnt[i], lc[i]);
}

// Exclusive scan of 392 bucket counts (pair trick); init cursors + rowptr[NN].
__global__ __launch_bounds__(256) void k_scanb(int* __restrict__ boff,
                                               int* __restrict__ bcur,
                                               int* __restrict__ rowptr) {
  __shared__ int sc[256];
  int t = threadIdx.x;
  int i0 = 2 * t, i1 = 2 * t + 1;
  int a = (i0 < 392) ? boff[i0] : 0;
  int b = (i1 < 392) ? boff[i1] : 0;
  sc[t] = a + b;
  __syncthreads();
  for (int off = 1; off < 256; off <<= 1) {
    int v = (t >= off) ? sc[t - off] : 0;
    __syncthreads();
    sc[t] += v;
    __syncthreads();
  }
  int excl = sc[t] - (a + b);
  if (i0 < 392) boff[i0] = excl;
  if (i1 < 392) boff[i1] = excl + a;
  if (i0 < NBK) bcur[i0] = excl;
  if (i1 < NBK) bcur[i1] = excl + a;
  if (t == 255) rowptr[NN] = sc[255];
}

// Partition edges into per-bucket regions via LDS staging (contiguous runs).
// rec = nin|rel<<16|local<<25 (ones) or e|local<<25 (generic).
__global__ __launch_bounds__(256) void k_parta(
    const int* __restrict__ el, int* __restrict__ bcur,
    int* __restrict__ eidx, const int* __restrict__ flags,
    const int* __restrict__ boff, int gb0, int gb1, int cap) {
  __shared__ int stage[CHUNK];
  __shared__ unsigned short sbk[CHUNK];
  __shared__ int lh[NBK], lbase[NBK], lh2[NBK], gbs[NBK];
  __shared__ int sc[256];
  __shared__ int total;
  int t = threadIdx.x;
  int nb = gb1 - gb0;
  int c0 = blockIdx.x * CHUNK;
  int ones = flags[5];
  int base0 = boff[gb0];
  for (int i = t; i < nb; i += 256) { lh[i] = 0; lh2[i] = 0; }
  __syncthreads();
  for (int i = t; i < CHUNK; i += 256) {
    int e = c0 + i;
    if (e < NE) {
      int b = (el[e * 3 + 1] >> 7) - gb0;
      if (b >= 0 && b < nb) atomicAdd(&lh[b], 1);
    }
  }
  __syncthreads();
  int a0 = (2 * t < nb) ? lh[2 * t] : 0;
  int a1 = (2 * t + 1 < nb) ? lh[2 * t + 1] : 0;
  sc[t] = a0 + a1;
  __syncthreads();
  for (int off = 1; off < 256; off <<= 1) {
    int v = (t >= off) ? sc[t - off] : 0;
    __syncthreads();
    sc[t] += v;
    __syncthreads();
  }
  int excl = sc[t] - (a0 + a1);
  if (2 * t < nb) {
    lbase[2 * t] = excl;
    if (a0 > 0) gbs[2 * t] = atomicAdd(&bcur[gb0 + 2 * t], a0);
  }
  if (2 * t + 1 < nb) {
    lbase[2 * t + 1] = excl + a0;
    if (a1 > 0) gbs[2 * t + 1] = atomicAdd(&bcur[gb0 + 2 * t + 1], a1);
  }
  if (t == 255) total = sc[255];
  __syncthreads();
  for (int i = t; i < CHUNK; i += 256) {
    int e = c0 + i;
    if (e < NE) {
      int nout = el[e * 3 + 1];
      int b = (nout >> 7) - gb0;
      if (b >= 0 && b < nb) {
        int r = atomicAdd(&lh2[b], 1);
        int slot = lbase[b] + r;
        int rec = ones ? (el[e * 3] | (el[e * 3 + 2] << 16) |
                          ((nout & 127) << 25))
                       : (e | ((nout & 127) << 25));
        stage[slot] = rec;
        sbk[slot] = (unsigned short)b;
      }
    }
  }
  __syncthreads();
  int tot = total;
  for (int i = t; i < tot; i += 256) {
    int b = sbk[i];
    int dst = gbs[b] + (i - lbase[b]) - base0;
    if (dst >= 0 && dst < cap) eidx[dst] = stage[i];
  }
}

// Per-bucket LDS counting sort by node; also writes per-node rowptr.
__global__ __launch_bounds__(256) void k_partb(
    int* __restrict__ eidx, const int* __restrict__ boff,
    int* __restrict__ rowptr, const int* __restrict__ el,
    const int* __restrict__ flags, int gb0, int cap) {
  __shared__ int ld[SBCAP];
  __shared__ int lcnt[128], lexc[128];
  int t = threadIdx.x;
  int b = gb0 + blockIdx.x;
  int n0 = b * 128;
  int ncnt = min(128, NN - n0);
  int base0 = boff[gb0];
  int rbase = boff[b], rend = boff[b + 1];
  int cnt = rend - rbase;
  int fast = (cnt <= SBCAP) && (rend - base0 <= cap);
  if (t < 128) lcnt[t] = 0;
  __syncthreads();
  if (fast) {
    for (int i = t; i < cnt; i += 256) ld[i] = eidx[rbase - base0 + i];
    __syncthreads();
    for (int i = t; i < cnt; i += 256)
      atomicAdd(&lcnt[(((unsigned)ld[i]) >> 25) & 127], 1);
  } else {
    int lim = n0 + ncnt;
    for (int e = t; e < NE; e += 256) {
      int nout = el[e * 3 + 1];
      if (nout >= n0 && nout < lim) atomicAdd(&lcnt[nout - n0], 1);
    }
  }
  __syncthreads();
  if (t < 128) lexc[t] = lcnt[t];
  __syncthreads();
  for (int off = 1; off < 128; off <<= 1) {
    int v = 0;
    if (t < 128 && t >= off) v = lexc[t - off];
    __syncthreads();
    if (t < 128) lexc[t] += v;
    __syncthreads();
  }
  if (t < 128) lexc[t] -= lcnt[t];
  __syncthreads();
  if (t < ncnt) rowptr[n0 + t] = rbase + lexc[t];
  if (t == 0) rowptr[n0 + ncnt] = rend;   // benign overlap with next bucket
  if (t < 128) lcnt[t] = 0;
  __syncthreads();
  if (fast) {
    for (int i = t; i < cnt; i += 256) {
      int rec = ld[i];
      int l = (((unsigned)rec) >> 25) & 127;
      int r = atomicAdd(&lcnt[l], 1);
      int dst = rbase + lexc[l] + r - base0;
      if (dst >= 0 && dst < cap) eidx[dst] = rec & 0x1FFFFFF;
    }
  } else {
    int ones = flags[5];
    int lim = n0 + ncnt;
    for (int e = t; e < NE; e += 256) {
      int nout = el[e * 3 + 1];
      if (nout >= n0 && nout < lim) {
        int l = nout - n0;
        int r = atomicAdd(&lcnt[l], 1);
        int dst = rbase + lexc[l] + r - base0;
        int rec = ones ? (el[e * 3] | (el[e * 3 + 2] << 16)) : e;
        if (dst >= 0 && dst < cap) eidx[dst] = rec;
      }
    }
  }
}

// 16 nodes per block (4 waves; wave wv does nodes 4wv..4wv+3's edge phase,
// then one 16x16 MFMA output tile). Grid stays wide (~3125 blocks/pass) —
// R9 lesson: fusing the bucket sort into this kernel collapsed occupancy
// (391 heavy blocks, 36KB LDS, 16%); keep sort in k_partb, epilogue in MFMA.
__global__ __launch_bounds__(256) void k_node(
    const void* __restrict__ input, const void* __restrict__ boundary,
    const int* __restrict__ el, const void* __restrict__ ew,
    const void* __restrict__ relw, const void* __restrict__ W,
    const void* __restrict__ bv, const int* __restrict__ rowptr,
    const int* __restrict__ eidx, const int* __restrict__ flags,
    void* __restrict__ out, int lo, int hi, int cap) {
  __shared__ __bf16 updb[16][72];   // stride 72 breaks epilogue aliasing

  int bfI = flags[0], bfB = flags[1], bfR = flags[2], bfW = flags[3],
      bfE = flags[4], ones = flags[5];
  int t  = threadIdx.x;
  int wv = t >> 6, ln = t & 63;
  int g  = ln >> 4;          // edge sub-slot group
  int k  = ln & 15;          // float4 index within the 64-dim row
  int q  = ln >> 4;          // MFMA quad
  int n0 = lo + blockIdx.x * 16;
  int base0 = rowptr[lo];

  // Per-wave epilogue B-fragments (cols cc = wv*16 + (ln&15)) and bias.
  // OUT[m][cc] = sum_k U[m][k]*W[cc][k]; B-frag[j] = W[cc][q*8+j].
  int cc = wv * 16 + (ln & 15);
  bf16x8 bfr0, bfr1;
  #pragma unroll
  for (int j = 0; j < 8; ++j) {
    bfr0[j] = (__bf16)loadF(W, cc * 64 + q * 8 + j, bfW);
    bfr1[j] = (__bf16)loadF(W, cc * 64 + 32 + q * 8 + j, bfW);
  }
  float bias = loadF(bv, cc, bfW);

  const float4* inp4 = (const float4*)input;
  const float4* rw4  = (const float4*)relw;
  int hot = (!bfI && !bfR && ones) ? 1 : 0;

  // ---- edge phase: 4 nodes per wave ----
  for (int rr = 0; rr < 4; ++rr) {
    int row = wv * 4 + rr;
    int n = n0 + row;
    if (n >= hi) {
      updb[row][ln] = (__bf16)0.0f;   // zero-pad row for the MFMA
      continue;
    }
    int start = rowptr[n] - base0, end = rowptr[n + 1] - base0;
    int deg = end - start;
    float4 s4 = {0.f,0.f,0.f,0.f}, q4 = {0.f,0.f,0.f,0.f};
    if (hot) {
      for (int base = start; base < end; base += 64) {
        int mm = end - base; if (mm > 64) mm = 64;
        int rec = 0;
        int idx2 = base + ln;
        if (ln < mm && idx2 < cap) rec = eidx[idx2];
        int jmax = (mm + 3) >> 2;
        #pragma unroll 8
        for (int j = 0; j < jmax; ++j) {
          int slot = j * 4 + g;
          int pk = __shfl(rec, slot);
          float wsel = (slot < mm) ? 1.0f : 0.0f;
          int nin = pk & 0xFFFF, rl = (pk >> 16) & 0x1FF;
          float4 a = inp4[nin * 16 + k];
          float4 r = rw4[rl * 16 + k];
          float tx = a.x*r.x, ty = a.y*r.y, tz = a.z*r.z, tw = a.w*r.w;
          s4.x = fmaf(wsel, tx, s4.x); q4.x = fmaf(wsel, tx*tx, q4.x);
          s4.y = fmaf(wsel, ty, s4.y); q4.y = fmaf(wsel, ty*ty, q4.y);
          s4.z = fmaf(wsel, tz, s4.z); q4.z = fmaf(wsel, tz*tz, q4.z);
          s4.w = fmaf(wsel, tw, s4.w); q4.w = fmaf(wsel, tw*tw, q4.w);
        }
      }
    } else {
      for (int base = start; base < end; base += 64) {
        int mm = end - base; if (mm > 64) mm = 64;
        int rec = 0; float wrec = 0.0f;
        int idx2 = base + ln;
        if (ln < mm && idx2 < cap) {
          rec = eidx[idx2] & 0x1FFFFFF;
          if (!ones) wrec = loadF(ew, rec, bfE);
        }
        int jmax = (mm + 3) >> 2;
        for (int j = 0; j < jmax; ++j) {
          int slot = j * 4 + g;
          int rj = __shfl(rec, slot);
          int nin, rl; float wj;
          if (ones) { nin = rj & 0xFFFF; rl = (rj >> 16) & 0x1FF; wj = 1.0f; }
          else      { nin = el[rj * 3]; rl = el[rj * 3 + 2];
                      wj = __shfl(wrec, slot); }
          float wsel = (slot < mm) ? wj : 0.0f;
          float4 a = loadF4(input, nin * 16 + k, bfI);
          float4 r = loadF4(relw, rl * 16 + k, bfR);
          float tx = a.x*r.x, ty = a.y*r.y, tz = a.z*r.z, tw = a.w*r.w;
          s4.x = fmaf(wsel, tx, s4.x); q4.x = fmaf(wsel*tx, tx, q4.x);
          s4.y = fmaf(wsel, ty, s4.y); q4.y = fmaf(wsel*ty, ty, q4.y);
          s4.z = fmaf(wsel, tz, s4.z); q4.z = fmaf(wsel*tz, tz, q4.z);
          s4.w = fmaf(wsel, tw, s4.w); q4.w = fmaf(wsel*tw, tw, q4.w);
        }
      }
    }
    s4.x += __shfl_xor(s4.x, 16); s4.x += __shfl_xor(s4.x, 32);
    s4.y += __shfl_xor(s4.y, 16); s4.y += __shfl_xor(s4.y, 32);
    s4.z += __shfl_xor(s4.z, 16); s4.z += __shfl_xor(s4.z, 32);
    s4.w += __shfl_xor(s4.w, 16); s4.w += __shfl_xor(s4.w, 32);
    q4.x += __shfl_xor(q4.x, 16); q4.x += __shfl_xor(q4.x, 32);
    q4.y += __shfl_xor(q4.y, 16); q4.y += __shfl_xor(q4.y, 32);
    q4.z += __shfl_xor(q4.z, 16); q4.z += __shfl_xor(q4.z, 32);
    q4.w += __shfl_xor(q4.w, 16); q4.w += __shfl_xor(q4.w, 32);
    if (g == 0) {
      float4 b4 = loadF4(boundary, n * 16 + k, bfB);
      float dg = (float)deg + 1.0f;
      float sv, qv;
      bf16x4 u;
      sv = (s4.x + b4.x) / dg; qv = (q4.x + b4.x * b4.x) / dg;
      u[0] = (__bf16)sqrtf(fmaxf(qv - sv * sv, 1e-6f));
      sv = (s4.y + b4.y) / dg; qv = (q4.y + b4.y * b4.y) / dg;
      u[1] = (__bf16)sqrtf(fmaxf(qv - sv * sv, 1e-6f));
      sv = (s4.z + b4.z) / dg; qv = (q4.z + b4.z * b4.z) / dg;
      u[2] = (__bf16)sqrtf(fmaxf(qv - sv * sv, 1e-6f));
      sv = (s4.w + b4.w) / dg; qv = (q4.w + b4.w * b4.w) / dg;
      u[3] = (__bf16)sqrtf(fmaxf(qv - sv * sv, 1e-6f));
      *(bf16x4*)&updb[row][4 * k] = u;
    }
  }
  __syncthreads();

  // ---- MFMA epilogue (layout verified in R9: absmax unchanged) ----
  bf16x8 af0 = *(const bf16x8*)&updb[ln & 15][q * 8];
  bf16x8 af1 = *(const bf16x8*)&updb[ln & 15][32 + q * 8];
  f32x4 acc = {0.f, 0.f, 0.f, 0.f};
  acc = __builtin_amdgcn_mfma_f32_16x16x32_bf16(af0, bfr0, acc, 0, 0, 0);
  acc = __builtin_amdgcn_mfma_f32_16x16x32_bf16(af1, bfr1, acc, 0, 0, 0);
  #pragma unroll
  for (int i = 0; i < 4; ++i) {
    int n = n0 + q * 4 + i;
    if (n < hi) {
      float v = acc[i] + bias;
      if (bfI) ((__hip_bfloat16*)out)[n * 64 + cc] = __float2bfloat16(v);
      else     ((float*)out)[n * 64 + cc] = v;
    }
  }
}

extern "C" void kernel_launch(void* const* d_in, const int* in_sizes, int n_in,
                              void* d_out, int out_size, void* d_ws, size_t ws_size,
                              hipStream_t stream) {
  const void* input    = d_in[0];
  const void* boundary = d_in[1];
  const int*  edges    = (const int*)d_in[2];
  const void* eweight  = d_in[3];
  const void* relw     = d_in[4];
  const void* W        = d_in[5];
  const void* bv       = d_in[6];

  int* wsI    = (int*)d_ws;
  int* flags  = wsI + OFF_FLAGS;
  int* boff   = wsI + OFF_BOFF;
  int* bcur   = wsI + OFF_BCUR;
  int* rowptr = wsI + OFF_ROWPTR;
  int* eidx   = wsI + OFF_EIDX;

  long cap = (long)(ws_size / 4) - OFF_EIDX;
  if (cap < 1) cap = 1;
  int npass;
  if      (cap >= (long)NE) npass = 1;
  else if (cap >= 1000000)  npass = 2;
  else if (cap >= 520000)   npass = 4;
  else                      npass = 8;

  k_detect<<<1, 64, 0, stream>>>(input, boundary, relw, W, eweight,
                                 flags, boff);
  k_bhist<<<(NE + 8191) / 8192, 256, 0, stream>>>(edges, eweight, boff, flags);
  k_scanb<<<1, 256, 0, stream>>>(boff, bcur, rowptr);

  const int PA_NB = (NE + CHUNK - 1) / CHUNK;
  for (int p = 0; p < npass; ++p) {
    int gb0 = NBK * p / npass;
    int gb1 = NBK * (p + 1) / npass;
    int lo = gb0 * 128;
    int hi = (gb1 * 128 < NN) ? gb1 * 128 : NN;
    k_parta<<<PA_NB, 256, 0, stream>>>(edges, bcur, eidx, flags, boff,
                                       gb0, gb1, (int)cap);
    k_partb<<<gb1 - gb0, 256, 0, stream>>>(eidx, boff, rowptr, edges, flags,
                                           gb0, (int)cap);
    k_node<<<(hi - lo + 15) / 16, 256, 0, stream>>>(
        input, boundary, edges, eweight, relw, W, bv, rowptr, eidx, flags,
        d_out, lo, hi, (int)cap);
  }
}